// Round 6
// baseline (103.369 us; speedup 1.0000x reference)
//
#include <hip/hip_runtime.h>
#include <math.h>

// Problem constants (fixed by the reference's setup_inputs)
constexpr int B = 2, G = 8, D = 16, H = 256, W = 320;
constexpr int HW = H * W;
constexpr float EPS = 1e-5f;
constexpr int WSTRIDE = 320;   // floats per folded-weight block (P at 0, S at 320)

__device__ __forceinline__ float sigmoidf_(float x) {
    return 1.0f / (1.0f + __expf(-x));
}

__device__ __forceinline__ int reflect_(int i, int n) {
    return i < 0 ? -i : (i >= n ? 2 * n - 2 - i : i);
}

// ---------------------------------------------------------------------------
// k_prep: fold BN (gamma / sqrt(1+eps)) into weights, pack into d_ws.
// Layout per net (stride WSTRIDE): W0f[0:128) W1f[128:256) W2[256:264)
// B0[264:280) B1[280:288) bias2[288].
// ---------------------------------------------------------------------------
__global__ __launch_bounds__(256) void k_prep(
    const float* __restrict__ sw0, const float* __restrict__ sg0, const float* __restrict__ sb0,
    const float* __restrict__ sw1, const float* __restrict__ sg1, const float* __restrict__ sb1,
    const float* __restrict__ sw2, const float* __restrict__ sbias2,
    const float* __restrict__ pw0, const float* __restrict__ pg0, const float* __restrict__ pb0,
    const float* __restrict__ pw1, const float* __restrict__ pg1, const float* __restrict__ pb1,
    const float* __restrict__ pw2, const float* __restrict__ pbias2,
    float* __restrict__ wbuf)
{
    const int t = threadIdx.x;
    const float rs = rsqrtf(1.0f + EPS);
    if (t < 128) {
        wbuf[t]                 = pw0[t] * pg0[t >> 3] * rs;
        wbuf[128 + t]           = pw1[t] * pg1[t >> 4] * rs;
        wbuf[WSTRIDE + t]       = sw0[t] * sg0[t >> 3] * rs;
        wbuf[WSTRIDE + 128 + t] = sw1[t] * sg1[t >> 4] * rs;
    } else {
        const int u = t - 128;
        if (u < 8) {
            wbuf[256 + u] = pw2[u];
            wbuf[WSTRIDE + 256 + u] = sw2[u];
        } else if (u < 24) {
            wbuf[264 + (u - 8)] = pb0[u - 8];
            wbuf[WSTRIDE + 264 + (u - 8)] = sb0[u - 8];
        } else if (u < 32) {
            wbuf[280 + (u - 24)] = pb1[u - 24];
            wbuf[WSTRIDE + 280 + (u - 24)] = sb1[u - 24];
        } else if (u == 32) {
            wbuf[288] = pbias2[0];
            wbuf[WSTRIDE + 288] = sbias2[0];
        }
    }
}

// ---------------------------------------------------------------------------
// 4-pixel MLP 8->16(ReLU)->8(ReLU)->1, weights from GLOBAL memory with
// wave-uniform indices (scalar/constant-cache loads; zero DS-pipe traffic).
// x is float4 = 4 adjacent pixels per group channel.
// ---------------------------------------------------------------------------
__device__ __forceinline__ float4 relu4_(float4 a) {
    return make_float4(fmaxf(a.x, 0.f), fmaxf(a.y, 0.f), fmaxf(a.z, 0.f), fmaxf(a.w, 0.f));
}
__device__ __forceinline__ void fma4_(float s, const float4& v, float4& a) {
    a.x = fmaf(s, v.x, a.x); a.y = fmaf(s, v.y, a.y);
    a.z = fmaf(s, v.z, a.z); a.w = fmaf(s, v.w, a.w);
}

__device__ __forceinline__ float4 mlp4_(const float* __restrict__ Wb, const float4 x[8])
{
    const float4* __restrict__ W0 = (const float4*)(Wb);         // 32
    const float4* __restrict__ W1 = (const float4*)(Wb + 128);   // 32
    const float4* __restrict__ W2 = (const float4*)(Wb + 256);   // 2
    const float* __restrict__ B0 = Wb + 264;
    const float* __restrict__ B1 = Wb + 280;
    const float bias2 = Wb[288];

    float4 l1[16];
    #pragma unroll
    for (int o = 0; o < 16; ++o) {
        const float4 wa = W0[o * 2 + 0];
        const float4 wb = W0[o * 2 + 1];
        const float bb = B0[o];
        float4 a = make_float4(bb, bb, bb, bb);
        fma4_(wa.x, x[0], a); fma4_(wa.y, x[1], a);
        fma4_(wa.z, x[2], a); fma4_(wa.w, x[3], a);
        fma4_(wb.x, x[4], a); fma4_(wb.y, x[5], a);
        fma4_(wb.z, x[6], a); fma4_(wb.w, x[7], a);
        l1[o] = relu4_(a);
    }
    float4 l2[8];
    #pragma unroll
    for (int o = 0; o < 8; ++o) {
        const float bb = B1[o];
        float4 a = make_float4(bb, bb, bb, bb);
        #pragma unroll
        for (int c4 = 0; c4 < 4; ++c4) {
            const float4 w = W1[o * 4 + c4];
            fma4_(w.x, l1[c4 * 4 + 0], a); fma4_(w.y, l1[c4 * 4 + 1], a);
            fma4_(w.z, l1[c4 * 4 + 2], a); fma4_(w.w, l1[c4 * 4 + 3], a);
        }
        l2[o] = relu4_(a);
    }
    float4 h = make_float4(bias2, bias2, bias2, bias2);
    #pragma unroll
    for (int c4 = 0; c4 < 2; ++c4) {
        const float4 w = W2[c4];
        fma4_(w.x, l2[c4 * 4 + 0], h); fma4_(w.y, l2[c4 * 4 + 1], h);
        fma4_(w.z, l2[c4 * 4 + 2], h); fma4_(w.w, l2[c4 * 4 + 3], h);
    }
    return h;
}

// ---------------------------------------------------------------------------
// Fused: PixelwiseNet + max-over-D + SimilarityNet, ONE read of x1.
// Block = 256 threads = 16 depths x 16 pixel-quads (64 consecutive pixels).
// Each thread: 4 pixels (float4) at 1 depth. Weights via uniform global
// loads (no LDS pipe). Max-over-D via a [16][16] float4 LDS tile.
// ---------------------------------------------------------------------------
__global__ __launch_bounds__(256) void k_fused(
    const float* __restrict__ x1,
    const float* __restrict__ depth_sample,
    const float* __restrict__ depth_min, const float* __restrict__ depth_max,
    const float* __restrict__ wP, const float* __restrict__ wS,
    float* __restrict__ s_out, float* __restrict__ xn_out)
{
    __shared__ float4 red[16][16];

    const int tid = threadIdx.x;
    const int q = tid & 15;           // pixel-quad lane (16 quads = 64 px)
    const int dt = tid >> 4;          // depth hypothesis 0..15
    const int pid0 = blockIdx.x * 64 + q * 4;   // global pixel over B*HW
    const int b = pid0 / HW;
    const int p0 = pid0 - b * HW;

    // ---- load 4 pixels x 8 groups of x1 (float4, coalesced) ----
    const float* xp = x1 + ((size_t)(b * G * D) + dt) * HW + p0;
    float4 xq[8];
    #pragma unroll
    for (int g = 0; g < 8; ++g)
        xq[g] = *reinterpret_cast<const float4*>(xp + (size_t)g * D * HW);

    // ---- PixelwiseNet head (sigmoid deferred; monotone) ----
    red[dt][q] = mlp4_(wP, xq);
    __syncthreads();

    // ---- max over 16 depth hypotheses per pixel ----
    float4 mx = red[0][q];
    #pragma unroll
    for (int k = 1; k < 16; ++k) {
        const float4 r = red[k][q];
        mx.x = fmaxf(mx.x, r.x); mx.y = fmaxf(mx.y, r.y);
        mx.z = fmaxf(mx.z, r.z); mx.w = fmaxf(mx.w, r.w);
    }
    const float4 vw = make_float4(sigmoidf_(mx.x), sigmoidf_(mx.y),
                                  sigmoidf_(mx.z), sigmoidf_(mx.w));

    // ---- SimilarityNet on x * vw (reuse registers) ----
    #pragma unroll
    for (int g = 0; g < 8; ++g) {
        xq[g].x *= vw.x; xq[g].y *= vw.y; xq[g].z *= vw.z; xq[g].w *= vw.w;
    }
    const float4 hS = mlp4_(wS, xq);

    const size_t oidx = (size_t)(b * D + dt) * HW + p0;
    *reinterpret_cast<float4*>(s_out + oidx) = hS;

    // ---- normalized inverse depth ----
    const float inv_min = 1.0f / depth_min[b];
    const float inv_max = 1.0f / depth_max[b];
    const float rinv = 1.0f / (inv_min - inv_max);
    const float4 ds = *reinterpret_cast<const float4*>(depth_sample + oidx);
    *reinterpret_cast<float4*>(xn_out + oidx) =
        make_float4((1.0f / ds.x - inv_max) * rinv,
                    (1.0f / ds.y - inv_max) * rinv,
                    (1.0f / ds.z - inv_max) * rinv,
                    (1.0f / ds.w - inv_max) * rinv);
}

// ---------------------------------------------------------------------------
// Kernel 3: neighbor gathers on s and xn, dw, score, softmax over D, depth.
// (unchanged)
// ---------------------------------------------------------------------------
__global__ __launch_bounds__(256) void k_score_depth(
    const float* __restrict__ s_arr, const float* __restrict__ xn,
    const float* __restrict__ offset, const float* __restrict__ depth_sample,
    float* __restrict__ out)
{
    __shared__ float off_lds[18][64];
    __shared__ float redA[4][64];
    __shared__ float redB[4][64];

    const int tid = threadIdx.x;
    const int pi = tid & 63;
    const int slot = tid >> 6;
    const int pg0_ = blockIdx.x * 64;
    const int b = pg0_ / HW;
    const int pb0 = pg0_ - b * HW;
    const int p = pb0 + pi;
    const int h = p / W;
    const int w = p - h * W;

    const float* ob = offset + (size_t)b * 18 * HW + pb0;
    for (int idx = tid; idx < 18 * 64; idx += 256) {
        const int s = idx >> 6, qq = idx & 63;
        off_lds[s][qq] = ob[(size_t)s * HW + qq];
    }
    __syncthreads();

    int a1s[9], a2s[9];
    {
        int ry1[3], ry2[3], cx1[3], cx2[3];
        #pragma unroll
        for (int i = 0; i < 3; ++i) {
            ry1[i] = reflect_(h + (i - 1) * 2, H) * W;
            ry2[i] = reflect_(h + (i - 1) * 4, H) * W;
            cx1[i] = reflect_(w + (i - 1) * 2, W);
            cx2[i] = reflect_(w + (i - 1) * 4, W);
        }
        #pragma unroll
        for (int s = 0; s < 9; ++s) {
            a1s[s] = ry1[s / 3] + cx1[s % 3];
            a2s[s] = ry2[s / 3] + cx2[s % 3];
        }
    }

    const size_t bbase = (size_t)b * D * HW;

    float score[4], dsv[4];
    #pragma unroll
    for (int i = 0; i < 4; ++i) {
        const int d = slot * 4 + i;
        const float* sd = s_arr + bbase + (size_t)d * HW;
        const float* xd = xn + bbase + (size_t)d * HW;
        float accs = 0.0f, accx = 0.0f;
        #pragma unroll
        for (int s = 0; s < 9; ++s) {
            const float w1 = off_lds[s + 9][pi];
            const float w2 = off_lds[s][pi];
            accs += 0.5f * (w1 * sd[a1s[s]] + w2 * sd[a2s[s]]);
            accx += 0.5f * (w1 * xd[a1s[s]] + w2 * xd[a2s[s]]);
        }
        const float xc = xd[p];
        const float diff = fminf(fabsf(accx - xc) * 40.0f, 4.0f);
        const float dwv = sigmoidf_((2.0f - diff) * 2.0f);
        score[i] = accs * dwv;
        dsv[i] = depth_sample[bbase + (size_t)d * HW + p];
    }

    float mp = fmaxf(fmaxf(score[0], score[1]), fmaxf(score[2], score[3]));
    redA[slot][pi] = mp;
    __syncthreads();
    const float m = fmaxf(fmaxf(redA[0][pi], redA[1][pi]),
                          fmaxf(redA[2][pi], redA[3][pi]));
    float sp = 0.0f, ap = 0.0f;
    #pragma unroll
    for (int i = 0; i < 4; ++i) {
        const float e = __expf(score[i] - m);
        sp += e;
        ap = fmaf(dsv[i], e, ap);
    }
    __syncthreads();
    redA[slot][pi] = sp;
    redB[slot][pi] = ap;
    __syncthreads();
    if (slot == 0) {
        const float sum = redA[0][pi] + redA[1][pi] + redA[2][pi] + redA[3][pi];
        const float acc = redB[0][pi] + redB[1][pi] + redB[2][pi] + redB[3][pi];
        out[pg0_ + pi] = acc / sum;
    }
}

// ---------------------------------------------------------------------------
extern "C" void kernel_launch(void* const* d_in, const int* in_sizes, int n_in,
                              void* d_out, int out_size, void* d_ws, size_t ws_size,
                              hipStream_t stream)
{
    const float* x1           = (const float*)d_in[0];
    const float* offset       = (const float*)d_in[1];
    const float* depth_sample = (const float*)d_in[2];
    const float* depth_min    = (const float*)d_in[3];
    const float* depth_max    = (const float*)d_in[4];
    const float* s_w0 = (const float*)d_in[5];
    const float* s_g0 = (const float*)d_in[6];
    const float* s_b0 = (const float*)d_in[7];
    const float* s_w1 = (const float*)d_in[8];
    const float* s_g1 = (const float*)d_in[9];
    const float* s_b1 = (const float*)d_in[10];
    const float* s_w2 = (const float*)d_in[11];
    const float* s_bias2 = (const float*)d_in[12];
    const float* p_w0 = (const float*)d_in[13];
    const float* p_g0 = (const float*)d_in[14];
    const float* p_b0 = (const float*)d_in[15];
    const float* p_w1 = (const float*)d_in[16];
    const float* p_g1 = (const float*)d_in[17];
    const float* p_b1 = (const float*)d_in[18];
    const float* p_w2 = (const float*)d_in[19];
    const float* p_bias2 = (const float*)d_in[20];

    float* s_arr = (float*)d_ws;                         // B*D*HW
    float* xn    = s_arr + (size_t)B * D * HW;           // B*D*HW
    float* wbuf  = xn + (size_t)B * D * HW;              // 2*WSTRIDE floats

    k_prep<<<1, 256, 0, stream>>>(
        s_w0, s_g0, s_b0, s_w1, s_g1, s_b1, s_w2, s_bias2,
        p_w0, p_g0, p_b0, p_w1, p_g1, p_b1, p_w2, p_bias2, wbuf);

    k_fused<<<(B * HW) / 64, 256, 0, stream>>>(
        x1, depth_sample, depth_min, depth_max,
        wbuf, wbuf + WSTRIDE, s_arr, xn);

    k_score_depth<<<(B * HW) / 64, 256, 0, stream>>>(
        s_arr, xn, offset, depth_sample, (float*)d_out);
}